// Round 12
// baseline (1766.356 us; speedup 1.0000x reference)
//
#include <hip/hip_runtime.h>
#include <hip/hip_fp16.h>
#include <hip/hip_cooperative_groups.h>

#define Sn 128
#define Bn 64
#define Hn 512
#define Vn 100
#define TSn 31   // T-1 steps

typedef unsigned int   u32;
typedef unsigned short u16;
typedef _Float16 f16x2 __attribute__((ext_vector_type(2)));
typedef _Float16 f16x8 __attribute__((ext_vector_type(8)));
typedef float    f32x4 __attribute__((ext_vector_type(4)));

// ---- ws byte offsets (~15.6 MB) ----
#define OFF_ENC2  0ull           // fp16 [64][128][512]  8,388,608  (enc transposed [B][S][H])
#define OFF_WC2M  8388608ull     // MFMA-packed ctx-half Wcomb: 512 tiles x 1KB = 524,288
#define OFF_WIHM  8912896ull     // MFMA-packed Wih: 1536 tiles = 1,572,864
#define OFF_WHHM  10485760ull    // MFMA-packed Whh: 1536 tiles = 1,572,864
#define OFF_WOUTM 12058624ull    // MFMA-packed Wout (v padded to 112): 112 tiles = 114,688
#define OFF_EMB2  12173312ull    // f32 [100][512] = 204,800  (Wcomb_emb @ Wemb^T + bcomb)
#define OFF_GB    12378112ull    // f32 [4][512] = 8,192      (folded gate biases)
#define OFF_PEX   12386304ull    // f32 [64][4][3072] = 3,145,728  (gate partials: ghR,Z,N giR,Z,N)
#define OFF_CNT   15532032ull    // u32 [64][16] = 4,096      (64B-padded barrier counters)

#define NT_IH 1536
#define NT_HH 1536
#define NT_C2 512
#define NT_OUT 112

__device__ __forceinline__ u16 f2h(float f){ _Float16 h=(_Float16)f; return __builtin_bit_cast(u16,h); }
__device__ __forceinline__ f16x2 uh2(u32 u){ return __builtin_bit_cast(f16x2,u); }
__device__ __forceinline__ float2 h2f(u32 u){ f16x2 h=uh2(u); return make_float2((float)h.x,(float)h.y); }
__device__ __forceinline__ u32 pack2h(float a, float b){ return (u32)f2h(a) | ((u32)f2h(b) << 16); }

__device__ __forceinline__ float fast_tanh(float x){
    float e = __expf(2.0f*x);
    return 1.0f - 2.0f/(e + 1.0f);
}
__device__ __forceinline__ float fast_sigmoid(float x){ return 1.0f/(1.0f + __expf(-x)); }

__device__ __forceinline__ float wave_sum(float v){
#pragma unroll
    for (int o = 32; o; o >>= 1) v += __shfl_xor(v, o);
    return v;
}
__device__ __forceinline__ float wave_max(float v){
#pragma unroll
    for (int o = 32; o; o >>= 1) v = fmaxf(v, __shfl_xor(v, o));
    return v;
}

__device__ __forceinline__ f32x4 mfma16(f16x8 a, f16x8 b, f32x4 c){
    return __builtin_amdgcn_mfma_f32_16x16x32_f16(a, b, c, 0, 0, 0);
}
__device__ __forceinline__ f16x8 ldB(const uint4* base, int tile, int lane){
    return __builtin_bit_cast(f16x8, base[(size_t)tile*64 + lane]);
}
// A fragment from a broadcast fp16 vector in LDS: elems [kf*32 + (lane>>4)*8 .. +8)
__device__ __forceinline__ f16x8 ldA(const u32* v32, int kf, int lane){
    return __builtin_bit_cast(f16x8, ((const uint4*)v32)[kf*4 + (lane>>4)]);
}

// ---- 4-sibling barrier (round-4 proven mechanism, verbatim) ----
__device__ __forceinline__ void sib_arrive(u32* cnt){
    asm volatile("s_waitcnt vmcnt(0)" ::: "memory");   // drain this wave's volatile stores
    __syncthreads();                                   // all waves drained
    if (threadIdx.x == 0)
        __hip_atomic_fetch_add(cnt, 1u, __ATOMIC_RELAXED, __HIP_MEMORY_SCOPE_AGENT);
}
__device__ __forceinline__ void sib_wait(u32* cnt, u32 target){
    if (threadIdx.x == 0) {
        u32 v;
        do { __builtin_amdgcn_s_sleep(2);
             v = __hip_atomic_load(cnt, __ATOMIC_RELAXED, __HIP_MEMORY_SCOPE_AGENT);
        } while (v < target);
    }
    __syncthreads();
}

// ---------------- prep 1: enc transpose -> fp16; folded gate biases; zero counters ----------------
__global__ __launch_bounds__(256) void prep_enc(
    const float* __restrict__ enc, const float* __restrict__ bih,
    const float* __restrict__ bhh, char* __restrict__ ws)
{
    const int t0 = blockIdx.x*256 + threadIdx.x;
    const int stride = gridDim.x*256;
    u16* de = (u16*)(ws + OFF_ENC2);
    for (int c = t0; c < Sn*Bn*Hn/4; c += stride) {
        const int h4 = c & 127;
        const int s  = (c >> 7) & 127;
        const int bb = c >> 14;
        float4 v = ((const float4*)enc)[(s*Bn + bb)*(Hn/4) + h4];
        ushort4 o;
        o.x = f2h(v.x); o.y = f2h(v.y); o.z = f2h(v.z); o.w = f2h(v.w);
        ((ushort4*)de)[c] = o;
    }
    float* GB = (float*)(ws + OFF_GB);
    for (int j = t0; j < Hn; j += stride) {
        GB[j]        = bih[j]        + bhh[j];
        GB[Hn + j]   = bih[Hn + j]   + bhh[Hn + j];
        GB[2*Hn + j] = bih[2*Hn + j];
        GB[3*Hn + j] = bhh[2*Hn + j];
    }
    u32* cnt = (u32*)(ws + OFF_CNT);
    for (int i = t0; i < 64*16; i += stride) cnt[i] = 0u;
}

// ---------------- prep 2: pack weights into MFMA B-fragment tiles (r10/r11-validated) ----------------
__global__ __launch_bounds__(256) void prep_pack(
    const float* __restrict__ Wih, const float* __restrict__ Whh,
    const float* __restrict__ Wcomb, const float* __restrict__ Wout,
    char* __restrict__ ws)
{
    const int total = (NT_IH + NT_HH + NT_C2 + NT_OUT)*64;
    for (int id = blockIdx.x*256 + threadIdx.x; id < total; id += gridDim.x*256) {
        const int l = id & 63;
        const int tile = id >> 6;
        const int kofs = ((l >> 4)*8);
        const float* s = nullptr;
        uint4* dst = nullptr;
        if (tile < NT_IH) {
            const int g = tile >> 9, jt = (tile >> 4) & 31, kf = tile & 15;
            s = Wih + ((size_t)(g*Hn + jt*16 + (l & 15)))*Hn + kf*32 + kofs;
            dst = (uint4*)(ws + OFF_WIHM) + (size_t)tile*64 + l;
        } else if (tile < NT_IH + NT_HH) {
            const int tt = tile - NT_IH;
            const int g = tt >> 9, jt = (tt >> 4) & 31, kf = tt & 15;
            s = Whh + ((size_t)(g*Hn + jt*16 + (l & 15)))*Hn + kf*32 + kofs;
            dst = (uint4*)(ws + OFF_WHHM) + (size_t)tt*64 + l;
        } else if (tile < NT_IH + NT_HH + NT_C2) {
            const int tt = tile - NT_IH - NT_HH;
            const int jt = tt >> 4, kf = tt & 15;
            s = Wcomb + ((size_t)(jt*16 + (l & 15)))*(2*Hn) + Hn + kf*32 + kofs;
            dst = (uint4*)(ws + OFF_WC2M) + (size_t)tt*64 + l;
        } else {
            const int tt = tile - NT_IH - NT_HH - NT_C2;
            const int jt = tt >> 4, kf = tt & 15;
            const int v = jt*16 + (l & 15);
            dst = (uint4*)(ws + OFF_WOUTM) + (size_t)tt*64 + l;
            if (v < Vn) s = Wout + (size_t)v*Hn + kf*32 + kofs;
        }
        uint4 val = {0u,0u,0u,0u};
        if (s) {
            const float4 a = *(const float4*)s;
            const float4 c = *(const float4*)(s + 4);
            val.x = pack2h(a.x, a.y); val.y = pack2h(a.z, a.w);
            val.z = pack2h(c.x, c.y); val.w = pack2h(c.z, c.w);
        }
        *dst = val;
    }
}

// ---------------- prep 3: EMB2[v][j] = Wcomb_emb[j,:]·Wemb[v,:] + bcomb[j] ----------------
__global__ __launch_bounds__(512) void prep_emb2(
    const float* __restrict__ Wemb, const float* __restrict__ Wcomb,
    const float* __restrict__ bcomb, char* __restrict__ ws)
{
    float* EMB2 = (float*)(ws + OFF_EMB2);
    const int w = threadIdx.x >> 6;
    const int lane = threadIdx.x & 63;
    const int j = blockIdx.x*8 + w;
    const float4* wc = (const float4*)(Wcomb + (size_t)j*2*Hn);
    const float bc = bcomb[j];
#pragma unroll
    for (int pass = 0; pass < 2; ++pass) {
        const int v = lane + 64*pass;
        if (v < Vn) {
            const float4* we = (const float4*)(Wemb + (size_t)v*Hn);
            float acc = 0.0f;
            for (int k4 = 0; k4 < 128; ++k4) {
                const float4 a = wc[k4], b = we[k4];
                acc += a.x*b.x + a.y*b.y + a.z*b.z + a.w*b.w;
            }
            EMB2[(size_t)v*Hn + j] = acc + bc;
        }
    }
}

// ---------------- main: 256 blocks x 1024 thr; 4 k-split siblings per b; ONE barrier/step ----------------
// xcd=bid&7, lb=bid>>3, q=xcd&3 (k-quarter kf in [4q,4q+4)), b=2*lb+(xcd>>2).
// h recurrence is fully block-local (redundant gate combine from exchanged f32 partials).
__global__ __launch_bounds__(1024) void bahdanau_decoder(
    const float* __restrict__ bout, const float* __restrict__ wvat,
    const float* __restrict__ bvat, const int* __restrict__ tgt,
    float* __restrict__ out, char* __restrict__ ws)
{
    const uint4* WC2M  = (const uint4*)(ws + OFF_WC2M);
    const uint4* WIHM  = (const uint4*)(ws + OFF_WIHM);
    const uint4* WHHM  = (const uint4*)(ws + OFF_WHHM);
    const uint4* WOUTM = (const uint4*)(ws + OFF_WOUTM);
    const float* EMB2  = (const float*)(ws + OFF_EMB2);
    const float* GB    = (const float*)(ws + OFF_GB);
    float* PEX = (float*)(ws + OFF_PEX);
    u32*   CNT = (u32*)(ws + OFF_CNT);

    extern __shared__ __align__(16) u16 enc_lds[];   // [128][512] fp16 = 131072 B
    __shared__ __align__(16) float h_full[Hn];       // fp32 master h (full, local)
    __shared__ __align__(16) u16   hn16[Hn];         // fp16 h (linear == A layout)
    __shared__ __align__(16) u16   xq[128];          // own x slice (k-quarter of gi)
    __shared__ __align__(16) u32   ctx32[Hn/2];      // fp16-pair ctx
    __shared__ __align__(16) float scores_s[Sn];
    __shared__ __align__(16) float attnw_s[Sn];
    __shared__ __align__(16) float2 pctx_s[4][256];
    __shared__ __align__(16) float sumR[Hn], sumZ[Hn], sumNh[Hn], sumNi[Hn];
    __shared__ __align__(16) float llog[128];

    const int tid  = threadIdx.x;
    const int lane = tid & 63;
    const int wid  = tid >> 6;              // 0..15
    const int bid  = blockIdx.x;
    const int xcd  = bid & 7;
    const int lb   = bid >> 3;
    const int q    = xcd & 3;               // k-quarter (XCD-resident weight slice)
    const int b    = 2*lb + (xcd >> 2);
    u32* cnt = CNT + b*16;
    const size_t pbase = ((size_t)b*4 + q)*3072;

    // enc slice -> LDS (read once, resident all steps)
    {
        const uint4* src = (const uint4*)(ws + OFF_ENC2 + (size_t)b*Sn*Hn*2);
        for (int i = tid; i < Sn*Hn/8; i += 1024) ((uint4*)enc_lds)[i] = src[i];
    }
    if (tid < Hn) { h_full[tid] = 0.0f; hn16[tid] = 0; }
    const float4 Wa = ((const float4*)wvat)[2*lane];
    const float4 Wb = ((const float4*)wvat)[2*lane+1];
    const float bv = bvat[0];
    __syncthreads();

    for (int t = 0; t < TSn; ++t) {
        // ===== Phase A (needs only h_t): field | gh partials | q0: logits+store =====
        if (wid < 4) {
            const float4 Ha = ((const float4*)h_full)[2*lane];
            const float4 Hb = ((const float4*)h_full)[2*lane+1];
            for (int i = 0; i < 32; ++i) {
                const int s = wid + 4*i;
                const uint4 E = ((const uint4*)(enc_lds + s*Hn))[lane];
                const float2 e0 = h2f(E.x), e1 = h2f(E.y), e2 = h2f(E.z), e3 = h2f(E.w);
                float acc = fast_tanh(e0.x+Ha.x)*Wa.x + fast_tanh(e0.y+Ha.y)*Wa.y
                          + fast_tanh(e1.x+Ha.z)*Wa.z + fast_tanh(e1.y+Ha.w)*Wa.w
                          + fast_tanh(e2.x+Hb.x)*Wb.x + fast_tanh(e2.y+Hb.y)*Wb.y
                          + fast_tanh(e3.x+Hb.z)*Wb.z + fast_tanh(e3.y+Hb.w)*Wb.w;
                acc = wave_sum(acc);
                if (lane == 0) scores_s[s] = acc + bv;
            }
        } else if (wid < 15) {
            // gh partials over own kf-quarter: tiles tt = (wid-4) + 11*i
            const int w = wid - 4;
#pragma unroll
            for (int i = 0; i < 9; ++i) {
                const int tt = w + 11*i;
                if (tt < 96) {
                    const int g = tt >> 5, jt = tt & 31;
                    f32x4 acc = {0.f,0.f,0.f,0.f};
#pragma unroll
                    for (int kfl = 0; kfl < 4; ++kfl)
                        acc = mfma16(ldA((const u32*)hn16, 4*q + kfl, lane),
                                     ldB(WHHM, (g*32 + jt)*16 + 4*q + kfl, lane), acc);
                    if (lane < 16)
                        ((volatile float*)PEX)[pbase + g*512 + jt*16 + lane] = acc[0];
                }
            }
        } else if (q == 0) {
            // wave 15 on q=0: full logits(h_t) -> out[t-1] (self-contained; r11-proven)
            if (t > 0) {
#pragma unroll
                for (int tt = 0; tt < 7; ++tt) {
                    f32x4 acc = {0.f,0.f,0.f,0.f};
#pragma unroll 4
                    for (int kf = 0; kf < 16; ++kf)
                        acc = mfma16(ldA((const u32*)hn16, kf, lane),
                                     ldB(WOUTM, tt*16 + kf, lane), acc);
                    if (lane < 16) {
                        const int v = tt*16 + lane;
                        if (v < Vn) llog[v] = acc[0] + bout[v];
                    }
                }
                const float l0 = llog[lane];
                const float l1 = (lane < 36) ? llog[64+lane] : -3.0e38f;
                const float mx = wave_max(fmaxf(l0, l1));
                const float e0 = __expf(l0 - mx);
                const float e1 = (lane < 36) ? __expf(l1 - mx) : 0.0f;
                const float lse = mx + __logf(wave_sum(e0 + e1));
                float* op = out + ((size_t)b*TSn + (t-1))*Vn;
                op[lane] = l0 - lse;
                if (lane < 36) op[64 + lane] = l1 - lse;
            }
        }
        __syncthreads();

        // ===== softmax (wave 0) =====
        if (wid == 0) {
            const float s0 = scores_s[lane], s1 = scores_s[lane+64];
            const float mx = wave_max(fmaxf(s0, s1));
            const float e0 = __expf(s0-mx), e1 = __expf(s1-mx);
            const float inv = 1.0f / wave_sum(e0 + e1);
            attnw_s[lane]    = e0 * inv;
            attnw_s[lane+64] = e1 * inv;
        }
        __syncthreads();

        // ===== ctx partials (all 1024 threads; r10-proven) =====
        {
            const int op = tid & 255, sc = tid >> 8;
            float ax = 0.0f, ay = 0.0f;
#pragma unroll 8
            for (int i2 = 0; i2 < 32; ++i2) {
                const int s = sc*32 + i2;
                const float a = attnw_s[s];
                const float2 ef = h2f(((const u32*)enc_lds)[s*256 + op]);
                ax += a*ef.x; ay += a*ef.y;
            }
            pctx_s[sc][op] = make_float2(ax, ay);
        }
        __syncthreads();
        if (tid < 256) {
            const float2 c0 = pctx_s[0][tid], c1 = pctx_s[1][tid];
            const float2 c2 = pctx_s[2][tid], c3 = pctx_s[3][tid];
            ctx32[tid] = pack2h(c0.x+c1.x+c2.x+c3.x, c0.y+c1.y+c2.y+c3.y);
        }
        __syncthreads();

        // ===== x own j-slice (j = k-quarter of gi): waves 0-7, one tile each =====
        {
            const int sym = tgt[t*Bn + b];
            if (wid < 8) {
                const int jt = 8*q + wid;
                f32x4 acc = {0.f,0.f,0.f,0.f};
#pragma unroll 4
                for (int kf = 0; kf < 16; ++kf)
                    acc = mfma16(ldA(ctx32, kf, lane), ldB(WC2M, jt*16 + kf, lane), acc);
                if (lane < 16) {
                    const int j = jt*16 + lane;
                    xq[wid*16 + lane] = f2h(fmaxf(acc[0] + EMB2[(size_t)sym*Hn + j], 0.0f));
                }
            }
        }
        __syncthreads();

        // ===== gi partials over own k-quarter (all 16 waves, 6 tiles each) =====
#pragma unroll
        for (int i = 0; i < 6; ++i) {
            const int tt = wid + 16*i;
            const int g = tt >> 5, jt = tt & 31;
            f32x4 acc = {0.f,0.f,0.f,0.f};
#pragma unroll
            for (int kfl = 0; kfl < 4; ++kfl)
                acc = mfma16(ldA((const u32*)xq, kfl, lane),
                             ldB(WIHM, (g*32 + jt)*16 + 4*q + kfl, lane), acc);
            if (lane < 16)
                ((volatile float*)PEX)[pbase + (3 + g)*512 + jt*16 + lane] = acc[0];
        }

        // ===== ONE barrier: all partials (gh published in phase A, gi just now) =====
        sib_arrive(cnt);
        sib_wait(cnt, 4u*(t+1));

        // ===== stage summed partials into LDS (all threads) =====
        {
            const volatile float* P = (const volatile float*)PEX + (size_t)b*4*3072;
            for (int p = tid; p < 2048; p += 1024) {
                const int kind = p >> 9, j = p & 511;
                float s = 0.0f;
                if (kind == 0) {
#pragma unroll
                    for (int q2 = 0; q2 < 4; ++q2)
                        s += P[q2*3072 + j] + P[q2*3072 + 3*512 + j];
                    sumR[j] = s;
                } else if (kind == 1) {
#pragma unroll
                    for (int q2 = 0; q2 < 4; ++q2)
                        s += P[q2*3072 + 512 + j] + P[q2*3072 + 4*512 + j];
                    sumZ[j] = s;
                } else if (kind == 2) {
#pragma unroll
                    for (int q2 = 0; q2 < 4; ++q2)
                        s += P[q2*3072 + 2*512 + j];
                    sumNh[j] = s;
                } else {
#pragma unroll
                    for (int q2 = 0; q2 < 4; ++q2)
                        s += P[q2*3072 + 5*512 + j];
                    sumNi[j] = s;
                }
            }
        }
        __syncthreads();

        // ===== redundant gate combine -> full h (block-local recurrence) =====
        if (tid < Hn) {
            const int j = tid;
            const float r = fast_sigmoid(sumR[j] + GB[j]);
            const float z = fast_sigmoid(sumZ[j] + GB[Hn + j]);
            const float n = fast_tanh(sumNi[j] + GB[2*Hn + j] + r*(sumNh[j] + GB[3*Hn + j]));
            const float hv = (1.0f - z)*n + z*h_full[j];
            h_full[j] = hv;
            hn16[j] = f2h(hv);
        }
        __syncthreads();
    }

    // ---- tail: logits + log-softmax for t = TSn-1 from final h (q=0, wave 15) ----
    if (q == 0 && wid == 15) {
#pragma unroll
        for (int tt = 0; tt < 7; ++tt) {
            f32x4 acc = {0.f,0.f,0.f,0.f};
#pragma unroll 4
            for (int kf = 0; kf < 16; ++kf)
                acc = mfma16(ldA((const u32*)hn16, kf, lane),
                             ldB(WOUTM, tt*16 + kf, lane), acc);
            if (lane < 16) {
                const int v = tt*16 + lane;
                if (v < Vn) llog[v] = acc[0] + bout[v];
            }
        }
        const float l0 = llog[lane];
        const float l1 = (lane < 36) ? llog[64+lane] : -3.0e38f;
        const float mx = wave_max(fmaxf(l0, l1));
        const float e0 = __expf(l0 - mx);
        const float e1 = (lane < 36) ? __expf(l1 - mx) : 0.0f;
        const float lse = mx + __logf(wave_sum(e0 + e1));
        float* op = out + ((size_t)b*TSn + (TSn-1))*Vn;
        op[lane] = l0 - lse;
        if (lane < 36) op[64 + lane] = l1 - lse;
    }
}

extern "C" void kernel_launch(void* const* d_in, const int* in_sizes, int n_in,
                              void* d_out, int out_size, void* d_ws, size_t ws_size,
                              hipStream_t stream) {
    const float* enc   = (const float*)d_in[0];
    const float* Wemb  = (const float*)d_in[1];
    const float* Wcomb = (const float*)d_in[2];
    const float* bcomb = (const float*)d_in[3];
    const float* Wih   = (const float*)d_in[4];
    const float* Whh   = (const float*)d_in[5];
    const float* bih   = (const float*)d_in[6];
    const float* bhh   = (const float*)d_in[7];
    const float* Wout  = (const float*)d_in[8];
    const float* bout  = (const float*)d_in[9];
    const float* wvat  = (const float*)d_in[10];
    const float* bvat  = (const float*)d_in[11];
    const int*   tgt   = (const int*)d_in[12];
    float* out = (float*)d_out;
    char*  ws  = (char*)d_ws;

    prep_enc<<<512, 256, 0, stream>>>(enc, bih, bhh, ws);
    prep_pack<<<512, 256, 0, stream>>>(Wih, Whh, Wcomb, Wout, ws);
    prep_emb2<<<64, 512, 0, stream>>>(Wemb, Wcomb, bcomb, ws);

    void* args[] = { &bout, &wvat, &bvat, &tgt, &out, &ws };
    hipLaunchCooperativeKernel((const void*)bahdanau_decoder,
                               dim3(256), dim3(1024), args, (size_t)(Sn*Hn*2), stream);
}